// Round 13
// baseline (48.149 us; speedup 1.0000x reference)
//
#include <hip/hip_runtime.h>
#include <hip/hip_bf16.h>

#define BATCH 16
#define FRAMES 8192
#define TLEN 512
#define EDIM 256
#define SPAD 72  // LDS row stride in shorts (144B): 16B-aligned

typedef __attribute__((ext_vector_type(8))) short short8;
typedef __attribute__((ext_vector_type(4))) float f32x4;

union U64x2S8 {
    unsigned long long u[2];
    short8 s;
};

__device__ __forceinline__ unsigned cvt2(float lo, float hi) {
    __hip_bfloat162 t = __float22bfloat162_rn(make_float2(lo, hi));  // v_cvt_pk_bf16_f32
    return *reinterpret_cast<unsigned*>(&t);
}
__device__ __forceinline__ short8 mk_s8(unsigned long long lo, unsigned long long hi) {
    U64x2S8 u;
    u.u[0] = lo;
    u.u[1] = hi;
    return u.s;
}
__device__ __forceinline__ unsigned long long pack4(f32x4 u) {
    return (unsigned long long)cvt2(u[0], u[1]) |
           ((unsigned long long)cvt2(u[2], u[3]) << 32);
}

// ---------------------------------------------------------------------------
// k0 (48 blocks x 256 thr):
//   blocks 0..31 : W -> bf16 twice: WbfI = bf16(W + I), Wbf = bf16(W)
//   blocks 32..47: aligner scan for batch (bid-32)  [r8-proven scan, verbatim]
// ---------------------------------------------------------------------------
__global__ __launch_bounds__(256) void k0(const float* __restrict__ W,
                                          const int* __restrict__ ap,
                                          const int* __restrict__ tp,
                                          short* __restrict__ WbfI,
                                          short* __restrict__ Wbf,
                                          int* __restrict__ inds) {
    int bid = blockIdx.x, tid = threadIdx.x;
    if (bid < 32) {
        int n0 = (bid * 256 + tid) * 8;  // 8 consecutive elems, same row d
        int d = n0 >> 8, e0 = n0 & 255;
        f32x4 u0 = *(const f32x4*)(W + n0);
        f32x4 u1 = *(const f32x4*)(W + n0 + 4);
        *(unsigned long long*)(Wbf + n0) = pack4(u0);
        *(unsigned long long*)(Wbf + n0 + 4) = pack4(u1);
        if (d >= e0 && d < e0 + 8) {  // diagonal element inside this chunk
            if (d < e0 + 4) u0[d - e0] += 1.0f;
            else            u1[d - e0 - 4] += 1.0f;
        }
        *(unsigned long long*)(WbfI + n0) = pack4(u0);
        *(unsigned long long*)(WbfI + n0 + 4) = pack4(u1);
        return;
    }
    // ---------------- aligner scan (r8-proven) ----------------
    __shared__ int tps[TLEN];
    __shared__ int wsum[4];
    __shared__ int okp;
    int b = bid - 32;
    const int* apb = ap + b * FRAMES;
    tps[tid] = tp[b * TLEN + tid];
    tps[tid + 256] = tp[b * TLEN + tid + 256];
    if (tid == 0) okp = 1;
    __syncthreads();
    int j0 = tid * 32;
    int a[32];
#pragma unroll
    for (int q = 0; q < 8; ++q)
        *(int4*)(a + q * 4) = ((const int4*)(apb + j0))[q];
    int pr = (tid == 0) ? a[0] : apb[j0 - 1];
    int cnt = 0, p[32];
#pragma unroll
    for (int k = 0; k < 32; ++k) {
        cnt += ((j0 + k) > 0) && (a[k] != pr);
        p[k] = cnt;
        pr = a[k];
    }
    int lane = tid & 63, wvi = tid >> 6;
    int sc = cnt;
#pragma unroll
    for (int d = 1; d < 64; d <<= 1) {
        int o = __shfl_up(sc, d);
        if (lane >= d) sc += o;
    }
    if (lane == 63) wsum[wvi] = sc;
    __syncthreads();
    int wbase = 0;
    for (int w = 0; w < wvi; ++w) wbase += wsum[w];
    int excl = wbase + sc - cnt;
    int g[32];
#pragma unroll
    for (int k = 0; k < 32; ++k) g[k] = min(excl + p[k], TLEN - 1);
    int4* ob = (int4*)(inds + b * FRAMES + j0);
#pragma unroll
    for (int q = 0; q < 8; ++q) {
        int4 o4;
        o4.x = g[q * 4]; o4.y = g[q * 4 + 1];
        o4.z = g[q * 4 + 2]; o4.w = g[q * 4 + 3];
        ob[q] = o4;
    }
    int ok = 1, gp = min(excl, TLEN - 1);
#pragma unroll
    for (int k = 0; k < 32; ++k) {
        int e;
        if (j0 + k == 0) e = 0;
        else e = (a[k] == tps[gp]) ? gp : min(gp + 1, TLEN - 1);
        ok &= (g[k] == e);
        gp = g[k];
    }
    if (!ok) atomicAnd(&okp, 0);
    __syncthreads();
    if (okp == 0 && tid == 0) {  // exact serial fallback (never for this input)
        int ind = 0, cur = tps[0];
        int* o = inds + b * FRAMES;
        o[0] = 0;
        for (int j = 1; j < FRAMES; ++j) {
            int aj = apb[j];
            if (aj != cur && ind < TLEN - 1) { ind++; cur = tps[ind]; }
            o[j] = ind;
        }
    }
}

// ---------------------------------------------------------------------------
// k_prep (256 blocks, 512 thr)  [r12 structure; W staged from preconverted
// bf16 via short8 copies — no per-block conversion, half the staging bytes]:
//   blocks 0..127   G[row][d] = sum_e enc[row][e]*WbfI[d][e]  (= enc + enc·Wt)
//   blocks 128..255 Q[f][d]   = sum_e PE[f][e]*Wbf[d][e] + pos_b[d]+pit_b[d]
// ---------------------------------------------------------------------------
__global__ __launch_bounds__(512) void k_prep(const float* __restrict__ X,
                                              const short* __restrict__ WbfI,
                                              const short* __restrict__ Wbf,
                                              const float* __restrict__ pos_b,
                                              const float* __restrict__ pit_b,
                                              float* __restrict__ G,
                                              float* __restrict__ Q) {
    __shared__ short lds[(64 + 256) * SPAD];  // 46080 B
    int bid = blockIdx.x;
    int tid = threadIdx.x;
    int qmode = (bid >= 128);
    int row0 = (qmode ? bid - 128 : bid) * 64;
    short* Xs = lds;              // 64 x SPAD
    short* Ws = lds + 64 * SPAD;  // 256 x SPAD
    int lane = tid & 63, wv = tid >> 6;
    int c = lane & 15, gq = lane >> 4;
    int r0 = (wv & 3) * 16, cc0 = (wv >> 2) * 128;
    int sr = tid >> 3, sp8 = (tid & 7) * 8;  // staging: 8 consecutive k-elems
    const short* Wb = qmode ? Wbf : WbfI;
    f32x4 acc[8];
#pragma unroll
    for (int i = 0; i < 8; ++i) acc[i] = (f32x4){0.f, 0.f, 0.f, 0.f};

    const float kPE = -0.03597789207803197f;     // -ln(10000)/256
    const float INV2PI = 0.15915494309189535f;

    for (int ks = 0; ks < 4; ++ks) {
        int k0 = ks * 64;
        __syncthreads();
        {   // stage X tile [64 r][64 k] (8 elems/thread)
            short8 xv;
            if (!qmode) {
                f32x4 u0 = *(const f32x4*)(X + (row0 + sr) * EDIM + k0 + sp8);
                f32x4 u1 = *(const f32x4*)(X + (row0 + sr) * EDIM + k0 + sp8 + 4);
                xv = mk_s8(pack4(u0), pack4(u1));
            } else {
                float fr = (float)(row0 + sr);
                unsigned pk[4];
#pragma unroll
                for (int jj = 0; jj < 4; ++jj) {
                    float dv = __expf((float)(k0 + sp8 + 2 * jj) * kPE);
                    float a0 = fr * dv * INV2PI;
                    a0 -= floorf(a0);
                    pk[jj] = cvt2(__builtin_amdgcn_sinf(a0), __builtin_amdgcn_cosf(a0));
                }
                xv = mk_s8((unsigned long long)pk[0] | ((unsigned long long)pk[1] << 32),
                           (unsigned long long)pk[2] | ((unsigned long long)pk[3] << 32));
            }
            *((short8*)&Xs[sr * SPAD + sp8]) = xv;
        }
#pragma unroll
        for (int m = 0; m < 4; ++m) {  // stage W tile [256 d][64 k]: bf16 copy
            int d = sr + 64 * m;
            *((short8*)&Ws[d * SPAD + sp8]) = *(const short8*)&Wb[d * EDIM + k0 + sp8];
        }
        __syncthreads();
#pragma unroll
        for (int ksub = 0; ksub < 2; ++ksub) {
            short8 af = *((const short8*)&Xs[(r0 + c) * SPAD + ksub * 32 + gq * 8]);
#pragma unroll
            for (int tc = 0; tc < 8; ++tc) {
                short8 bf = *((const short8*)&Ws[(cc0 + tc * 16 + c) * SPAD + ksub * 32 + gq * 8]);
                acc[tc] = __builtin_amdgcn_mfma_f32_16x16x32_bf16(af, bf, acc[tc], 0, 0, 0);
            }
        }
    }
    // epilogue: C/D layout col=lane&15, row=(lane>>4)*4+i
    int mrow = row0 + r0 + gq * 4;
    if (!qmode) {
#pragma unroll
        for (int tc = 0; tc < 8; ++tc) {
            int d = cc0 + tc * 16 + c;
#pragma unroll
            for (int i = 0; i < 4; ++i)
                G[(mrow + i) * EDIM + d] = acc[tc][i];
        }
    } else {
#pragma unroll
        for (int tc = 0; tc < 8; ++tc) {
            int d = cc0 + tc * 16 + c;
            float bb = pos_b[d] + pit_b[d];
#pragma unroll
            for (int i = 0; i < 4; ++i)
                Q[(mrow + i) * EDIM + d] = acc[tc][i] + bb;
        }
    }
}

// ---------------------------------------------------------------------------
// k_final v4 (r7/r12 proven) + nontemporal out stores: 2048 blocks x 256 thr;
// block owns 4 frames x 16 batches; wave owns 4 batches. XCD-chunked swizzle.
// out[b,f,:] = G[b,ind,:] + Q[f,:] + pitch*wp + EB[beat]
// ---------------------------------------------------------------------------
__global__ __launch_bounds__(256) void k_final(const float* __restrict__ G,
                                               const float* __restrict__ Q,
                                               const int* __restrict__ inds,
                                               const float* __restrict__ pitch,
                                               const int* __restrict__ beats,
                                               const float* __restrict__ wp,
                                               const float* __restrict__ eb,
                                               float* __restrict__ out) {
    int swz = (blockIdx.x & 7) * 256 + (blockIdx.x >> 3);
    int f0 = swz * 4;
    int wv = threadIdx.x >> 6, lane = threadIdx.x & 63;
    f32x4 w4 = ((const f32x4*)wp)[lane];
    f32x4 e0v = ((const f32x4*)eb)[lane];
    f32x4 e1v = ((const f32x4*)eb)[64 + lane];
    f32x4 q[4];
#pragma unroll
    for (int f = 0; f < 4; ++f) q[f] = ((const f32x4*)Q)[(f0 + f) * 64 + lane];
#pragma unroll
    for (int bb = 0; bb < 4; ++bb) {
        int b = wv * 4 + bb;
        int idx0 = b * FRAMES + f0;
        int4 iv = *(const int4*)(inds + idx0);
        f32x4 pv4 = *(const f32x4*)(pitch + idx0);
        int4 tv = *(const int4*)(beats + idx0);
        int indv[4] = {iv.x, iv.y, iv.z, iv.w};
        float pv[4] = {pv4[0], pv4[1], pv4[2], pv4[3]};
        int btv[4] = {tv.x, tv.y, tv.z, tv.w};
#pragma unroll
        for (int f = 0; f < 4; ++f) {
            f32x4 g = ((const f32x4*)G)[(b * TLEN + indv[f]) * 64 + lane];
            f32x4 e = btv[f] ? e1v : e0v;
            f32x4 r;
#pragma unroll
            for (int i = 0; i < 4; ++i) r[i] = g[i] + q[f][i] + pv[f] * w4[i] + e[i];
            __builtin_nontemporal_store(r, &((f32x4*)out)[(idx0 + f) * 64 + lane]);
        }
    }
}

extern "C" void kernel_launch(void* const* d_in, const int* in_sizes, int n_in,
                              void* d_out, int out_size, void* d_ws, size_t ws_size,
                              hipStream_t stream) {
    const float* enc   = (const float*)d_in[0];  // [16,512,256]
    const int*   ap    = (const int*)d_in[1];    // [16,8192]
    const int*   tp    = (const int*)d_in[2];    // [16,512]
    const float* pitch = (const float*)d_in[3];  // [16,8192,1]
    const int*   beats = (const int*)d_in[4];    // [16,8192,1]
    const float* wpit  = (const float*)d_in[5];  // [256,1]
    const float* bpit  = (const float*)d_in[6];  // [256]
    const float* wpos  = (const float*)d_in[7];  // [256,256]
    const float* bpos  = (const float*)d_in[8];  // [256]
    const float* ebts  = (const float*)d_in[9];  // [2,256]
    float* out = (float*)d_out;
    char* ws = (char*)d_ws;
    int*   inds = (int*)ws;                          // 512 KB
    float* G    = (float*)(ws + (1 << 20));          // 8 MB
    float* Q    = (float*)(ws + (9 << 20));          // 8 MB
    short* WbfI = (short*)(ws + (17 << 20));         // 128 KB
    short* Wbf  = (short*)(ws + (17 << 20) + (128 << 10));  // 128 KB

    hipLaunchKernelGGL(k0, dim3(48), dim3(256), 0, stream,
                       wpos, ap, tp, WbfI, Wbf, inds);
    hipLaunchKernelGGL(k_prep, dim3(256), dim3(512), 0, stream,
                       enc, WbfI, Wbf, bpos, bpit, G, Q);
    hipLaunchKernelGGL(k_final, dim3(2048), dim3(256), 0, stream,
                       G, Q, inds, pitch, beats, wpit, ebts, out);
}

// Round 14
// 42.043 us; speedup vs baseline: 1.1452x; 1.1452x over previous
//
#include <hip/hip_runtime.h>
#include <hip/hip_bf16.h>

#define BATCH 16
#define FRAMES 8192
#define TLEN 512
#define EDIM 256
#define SPAD 72  // LDS row stride in shorts (144B): 16B-aligned

typedef __attribute__((ext_vector_type(8))) short short8;
typedef __attribute__((ext_vector_type(4))) float f32x4;

union U64x2S8 {
    unsigned long long u[2];
    short8 s;
};

__device__ __forceinline__ unsigned cvt2(float lo, float hi) {
    __hip_bfloat162 t = __float22bfloat162_rn(make_float2(lo, hi));  // v_cvt_pk_bf16_f32
    return *reinterpret_cast<unsigned*>(&t);
}
__device__ __forceinline__ short8 mk_s8(unsigned long long lo, unsigned long long hi) {
    U64x2S8 u;
    u.u[0] = lo;
    u.u[1] = hi;
    return u.s;
}
__device__ __forceinline__ unsigned long long pack4(f32x4 u) {
    return (unsigned long long)cvt2(u[0], u[1]) |
           ((unsigned long long)cvt2(u[2], u[3]) << 32);
}

// ---------------------------------------------------------------------------
// k_prep (256 blocks, 512 thr):
//   blocks 0..127   G[row][d] = sum_e enc[row][e]*(W+I)[d][e]  (= enc + enc·Wt)
//   blocks 128..255 Q[f][d]   = sum_e PE[f][e]*W[d][e] + pos_b[d]+pit_b[d]
//   blocks 240..255 ALSO run the aligner scan for batch (bid-240) BEFORE GEMM
// GEMM: r2-proven wave layout (8 waves: 4 row-groups x 2 col-halves),
// K-chunk 64 single-buffered (8 barriers instead of 16), cvt_pk staging.
// ---------------------------------------------------------------------------
__global__ __launch_bounds__(512) void k_prep(const float* __restrict__ X,
                                              const float* __restrict__ W,
                                              const float* __restrict__ pos_b,
                                              const float* __restrict__ pit_b,
                                              const int* __restrict__ ap,
                                              const int* __restrict__ tp,
                                              float* __restrict__ G,
                                              float* __restrict__ Q,
                                              int* __restrict__ inds) {
    __shared__ short lds[(64 + 256) * SPAD];  // 46080 B
    int bid = blockIdx.x;
    int tid = threadIdx.x;

    if (bid >= 240) {
        // ---------------- aligner scan (r7-proven, then fall through) -------
        int b = bid - 240;
        int* tps = (int*)lds;          // 512 ints
        int* wsum = tps + TLEN;        // 8 ints
        int* okp = wsum + 8;
        const int* apb = ap + b * FRAMES;
        tps[tid] = tp[b * TLEN + tid];
        if (tid == 0) *okp = 1;
        __syncthreads();
        int j0 = tid * 16;
        int4 v0 = ((const int4*)apb)[tid * 4];
        int4 v1 = ((const int4*)apb)[tid * 4 + 1];
        int4 v2 = ((const int4*)apb)[tid * 4 + 2];
        int4 v3 = ((const int4*)apb)[tid * 4 + 3];
        int a[16] = {v0.x, v0.y, v0.z, v0.w, v1.x, v1.y, v1.z, v1.w,
                     v2.x, v2.y, v2.z, v2.w, v3.x, v3.y, v3.z, v3.w};
        int pr = (tid == 0) ? a[0] : apb[j0 - 1];
        int c = 0, p[16];
#pragma unroll
        for (int k = 0; k < 16; ++k) {
            c += ((j0 + k) > 0) && (a[k] != pr);
            p[k] = c;
            pr = a[k];
        }
        int lane = tid & 63, wv = tid >> 6;
        int sc = c;
#pragma unroll
        for (int d = 1; d < 64; d <<= 1) {
            int o = __shfl_up(sc, d);
            if (lane >= d) sc += o;
        }
        if (lane == 63) wsum[wv] = sc;
        __syncthreads();
        int wbase = 0;
        for (int w = 0; w < wv; ++w) wbase += wsum[w];
        int excl = wbase + sc - c;
        int g[16];
#pragma unroll
        for (int k = 0; k < 16; ++k) g[k] = min(excl + p[k], TLEN - 1);
        int4* ob = (int4*)(inds + b * FRAMES);
#pragma unroll
        for (int q4 = 0; q4 < 4; ++q4) {
            int4 wv4;
            wv4.x = g[q4 * 4]; wv4.y = g[q4 * 4 + 1];
            wv4.z = g[q4 * 4 + 2]; wv4.w = g[q4 * 4 + 3];
            ob[tid * 4 + q4] = wv4;
        }
        int ok = 1, gp = min(excl, TLEN - 1);
#pragma unroll
        for (int k = 0; k < 16; ++k) {
            int j = j0 + k, e;
            if (j == 0) e = 0;
            else e = (a[k] == tps[gp]) ? gp : min(gp + 1, TLEN - 1);
            ok &= (g[k] == e);
            gp = g[k];
        }
        if (!ok) atomicAnd(okp, 0);
        __syncthreads();
        if (*okp == 0 && tid == 0) {  // exact serial fallback (never for this input)
            int ind = 0, cur = tps[0];
            int* o = inds + b * FRAMES;
            o[0] = 0;
            for (int j = 1; j < FRAMES; ++j) {
                int aj = apb[j];
                if (aj != cur && ind < TLEN - 1) { ind++; cur = tps[ind]; }
                o[j] = ind;
            }
        }
        // fall through to GEMM (first loop iteration starts with __syncthreads)
    }

    // ---------------- GEMM path ----------------
    int qmode = (bid >= 128);
    int row0 = (qmode ? bid - 128 : bid) * 64;
    short* Xs = lds;              // 64 x SPAD
    short* Ws = lds + 64 * SPAD;  // 256 x SPAD
    int lane = tid & 63, wv = tid >> 6;
    int c = lane & 15, gq = lane >> 4;
    int r0 = (wv & 3) * 16, cc0 = (wv >> 2) * 128;
    int sr = tid >> 3, sp8 = (tid & 7) * 8;  // staging: 8 consecutive k-elems
    f32x4 acc[8];
#pragma unroll
    for (int i = 0; i < 8; ++i) acc[i] = (f32x4){0.f, 0.f, 0.f, 0.f};

    const float kPE = -0.03597789207803197f;     // -ln(10000)/256
    const float INV2PI = 0.15915494309189535f;

    for (int ks = 0; ks < 4; ++ks) {
        int k0 = ks * 64;
        __syncthreads();
        {   // stage X tile [64 r][64 k] (8 elems/thread)
            short8 xv;
            if (!qmode) {
                f32x4 u0 = *(const f32x4*)(X + (row0 + sr) * EDIM + k0 + sp8);
                f32x4 u1 = *(const f32x4*)(X + (row0 + sr) * EDIM + k0 + sp8 + 4);
                xv = mk_s8(pack4(u0), pack4(u1));
            } else {
                float fr = (float)(row0 + sr);
                unsigned pk[4];
#pragma unroll
                for (int jj = 0; jj < 4; ++jj) {
                    float dv = __expf((float)(k0 + sp8 + 2 * jj) * kPE);
                    float a0 = fr * dv * INV2PI;
                    a0 -= floorf(a0);
                    pk[jj] = cvt2(__builtin_amdgcn_sinf(a0), __builtin_amdgcn_cosf(a0));
                }
                xv = mk_s8((unsigned long long)pk[0] | ((unsigned long long)pk[1] << 32),
                           (unsigned long long)pk[2] | ((unsigned long long)pk[3] << 32));
            }
            *((short8*)&Xs[sr * SPAD + sp8]) = xv;
        }
#pragma unroll
        for (int m = 0; m < 4; ++m) {  // stage W tile [256 d][64 k], +I for G-path
            int d = sr + 64 * m;
            f32x4 u0 = *(const f32x4*)(W + d * EDIM + k0 + sp8);
            f32x4 u1 = *(const f32x4*)(W + d * EDIM + k0 + sp8 + 4);
            if (!qmode) {
#pragma unroll
                for (int j = 0; j < 4; ++j) {
                    if (d == k0 + sp8 + j) u0[j] += 1.0f;
                    if (d == k0 + sp8 + 4 + j) u1[j] += 1.0f;
                }
            }
            *((short8*)&Ws[d * SPAD + sp8]) = mk_s8(pack4(u0), pack4(u1));
        }
        __syncthreads();
#pragma unroll
        for (int ksub = 0; ksub < 2; ++ksub) {
            short8 af = *((const short8*)&Xs[(r0 + c) * SPAD + ksub * 32 + gq * 8]);
#pragma unroll
            for (int tc = 0; tc < 8; ++tc) {
                short8 bf = *((const short8*)&Ws[(cc0 + tc * 16 + c) * SPAD + ksub * 32 + gq * 8]);
                acc[tc] = __builtin_amdgcn_mfma_f32_16x16x32_bf16(af, bf, acc[tc], 0, 0, 0);
            }
        }
    }
    // epilogue: C/D layout col=lane&15, row=(lane>>4)*4+i
    int mrow = row0 + r0 + gq * 4;
    if (!qmode) {
#pragma unroll
        for (int tc = 0; tc < 8; ++tc) {
            int d = cc0 + tc * 16 + c;
#pragma unroll
            for (int i = 0; i < 4; ++i)
                G[(mrow + i) * EDIM + d] = acc[tc][i];
        }
    } else {
#pragma unroll
        for (int tc = 0; tc < 8; ++tc) {
            int d = cc0 + tc * 16 + c;
            float bb = pos_b[d] + pit_b[d];
#pragma unroll
            for (int i = 0; i < 4; ++i)
                Q[(mrow + i) * EDIM + d] = acc[tc][i] + bb;
        }
    }
}

// ---------------------------------------------------------------------------
// k_final v4 (round-7 proven, verbatim): 2048 blocks x 256 thr; block owns
// 4 frames x 16 batches; wave owns 4 batches. XCD-chunked bijective swizzle.
// out[b,f,:] = G[b,ind,:] + Q[f,:] + pitch*wp + EB[beat]
// ---------------------------------------------------------------------------
__global__ __launch_bounds__(256) void k_final(const float* __restrict__ G,
                                               const float* __restrict__ Q,
                                               const int* __restrict__ inds,
                                               const float* __restrict__ pitch,
                                               const int* __restrict__ beats,
                                               const float* __restrict__ wp,
                                               const float* __restrict__ eb,
                                               float* __restrict__ out) {
    int swz = (blockIdx.x & 7) * 256 + (blockIdx.x >> 3);
    int f0 = swz * 4;
    int wv = threadIdx.x >> 6, lane = threadIdx.x & 63;
    f32x4 w4 = ((const f32x4*)wp)[lane];
    f32x4 e0v = ((const f32x4*)eb)[lane];
    f32x4 e1v = ((const f32x4*)eb)[64 + lane];
    f32x4 q[4];
#pragma unroll
    for (int f = 0; f < 4; ++f) q[f] = ((const f32x4*)Q)[(f0 + f) * 64 + lane];
#pragma unroll
    for (int bb = 0; bb < 4; ++bb) {
        int b = wv * 4 + bb;
        int idx0 = b * FRAMES + f0;
        int4 iv = *(const int4*)(inds + idx0);
        f32x4 pv4 = *(const f32x4*)(pitch + idx0);
        int4 tv = *(const int4*)(beats + idx0);
        int indv[4] = {iv.x, iv.y, iv.z, iv.w};
        float pv[4] = {pv4[0], pv4[1], pv4[2], pv4[3]};
        int btv[4] = {tv.x, tv.y, tv.z, tv.w};
#pragma unroll
        for (int f = 0; f < 4; ++f) {
            f32x4 g = ((const f32x4*)G)[(b * TLEN + indv[f]) * 64 + lane];
            f32x4 e = btv[f] ? e1v : e0v;
            f32x4 r;
#pragma unroll
            for (int i = 0; i < 4; ++i) r[i] = g[i] + q[f][i] + pv[f] * w4[i] + e[i];
            ((f32x4*)out)[(idx0 + f) * 64 + lane] = r;
        }
    }
}

extern "C" void kernel_launch(void* const* d_in, const int* in_sizes, int n_in,
                              void* d_out, int out_size, void* d_ws, size_t ws_size,
                              hipStream_t stream) {
    const float* enc   = (const float*)d_in[0];  // [16,512,256]
    const int*   ap    = (const int*)d_in[1];    // [16,8192]
    const int*   tp    = (const int*)d_in[2];    // [16,512]
    const float* pitch = (const float*)d_in[3];  // [16,8192,1]
    const int*   beats = (const int*)d_in[4];    // [16,8192,1]
    const float* wpit  = (const float*)d_in[5];  // [256,1]
    const float* bpit  = (const float*)d_in[6];  // [256]
    const float* wpos  = (const float*)d_in[7];  // [256,256]
    const float* bpos  = (const float*)d_in[8];  // [256]
    const float* ebts  = (const float*)d_in[9];  // [2,256]
    float* out = (float*)d_out;
    char* ws = (char*)d_ws;
    int*   inds = (int*)ws;                   // 512 KB
    float* G    = (float*)(ws + (1 << 20));   // 8 MB
    float* Q    = (float*)(ws + (9 << 20));   // 8 MB

    hipLaunchKernelGGL(k_prep, dim3(256), dim3(512), 0, stream,
                       enc, wpos, bpos, bpit, ap, tp, G, Q, inds);
    hipLaunchKernelGGL(k_final, dim3(2048), dim3(256), 0, stream,
                       G, Q, inds, pitch, beats, wpit, ebts, out);
}